// Round 10
// baseline (156.111 us; speedup 1.0000x reference)
//
#include <hip/hip_runtime.h>

// VectorQuantizer: N=131072 tokens, D=64, K=1024 codes.
// out (f32 concat): [0,8388608) quant, [8388608] loss, [8388609,...) idx.
//
// R20: 32x32x16 MFMA restructure.
// R19 post-mortem: 8th schedule null. Counter forensics: VALUBusy ~= 1.1-1.3x
// MfmaUtil in EVERY config incl. the R13 spill run -> VALUBusy includes MFMA
// execution; real VALU ~6%. So the wall = MFMA 31% + VALU 6% + ~60%
// unattributed per-tile stall, invariant under occupancy/prefetch-depth/
// LDS-vs-reg/setprio/SGB. The stall scales with tile count.
// R20 halves tile+instruction count and gains ~11% pipe rate by moving to
// v_mfma_f32_32x32x16_f16: 32 tiles x 32 codes, 12 MFMA/tile (vs 64 tiles,
// 12 MFMA covering half the codes). C/D layout per m74/m101 (HW-verified):
// col=lane&31, row=(reg&3)+8*(reg>>2)+4*(lane>>5). A/B layouts extrapolated
// from this kernel's proven 16x16x32 pattern (M/N in low lane bits, k-chunk
// = lane>>5, 8 contiguous k per frag).
// NOT bit-identical (the only such change this session): K regrouped into
// 16-chunks shifts dots by ~1e-7 (100x below the tolerated fp16-split
// error); grid-quantized distances (ulp 7.6e-6) should absorb it. Tie
// semantics preserved: strict <, ascending tiles, u64-key butterfly picks
// smallest idx on equal distance.
// No LDS in main (e2 streamed per tile from ws, x2 via wave shuffles);
// half-tile B dbuf (B_hi dead after lo*hi -> prefetch into it);
// launch_bounds(256,1) -- R16 lesson: never cap the allocator below the
// live set (~145 VGPR est). Gates next round: VGPR 130-170, FETCH ~18.5MB.
// Distance expressions unchanged: fp16 split (hi*hi+lo*hi+hi*lo),
// np8 x2/e2, s=fma(-2,acc,x2v+e2v), first-min, bitwise quant copy,
// atomicAdd loss fusion. 2 launches.

#define KC 1024
#define DD 64
#define NTOK (32 * 4096)
#define QUANT_ELEMS ((size_t)NTOK * DD)        // 8388608
#define LOSS_OFF QUANT_ELEMS
#define IDX_OFF (QUANT_ELEMS + 1)

// ws float-word offsets
#define WS_E2 0                      // 1024 f32
#define WS_BFRAG_F 2048              // 16384 f16x8 = 65536 f32 words

#define MAIN_BLOCKS (NTOK / 128)     // 1024 blocks, 128 tokens each

typedef _Float16 f16x8 __attribute__((ext_vector_type(8)));
typedef float f32x16 __attribute__((ext_vector_type(16)));

#define MFMA32 __builtin_amdgcn_mfma_f32_32x32x16_f16

__device__ __forceinline__ unsigned int sortable_bits(float f) {
  unsigned int b = __float_as_uint(f);
  return b ^ (unsigned int)(((int)b >> 31) | 0x80000000);
}

__device__ __forceinline__ float unsortable_bits(unsigned int u) {
  unsigned int fb = (u & 0x80000000u) ? (u ^ 0x80000000u) : ~u;
  return __uint_as_float(fb);
}

// np pairwise-8 sum of squares of a 64-float row (bit-identical to R10)
__device__ __forceinline__ float row_sumsq_np8(const float* p) {
  float r[8];
#pragma unroll
  for (int j = 0; j < 8; ++j) r[j] = p[j] * p[j];
#pragma unroll
  for (int i = 1; i < 8; ++i)
#pragma unroll
    for (int j = 0; j < 8; ++j) {
      float v = p[i * 8 + j];
      r[j] += v * v;
    }
  return ((r[0] + r[1]) + (r[2] + r[3])) + ((r[4] + r[5]) + (r[6] + r[7]));
}

// blocks [0,32): 32x32 B-frag build; [32,36): e2 table + loss zero.
// Frag (tile T, plane p, kchunk q) at [(T*8+p*4+q)*64+lane]:
// code = T*32+(lane&31), dims = q*16+(lane>>5)*8 .. +8.
__global__ void vq_setup(const float* __restrict__ emb,
                         float* __restrict__ ws,
                         float* __restrict__ out) {
  const int b = blockIdx.x;
  const int tid = threadIdx.x;
  if (b < 32) {
    const int T = b;
    const int q = tid >> 6;            // 0..3
    const int lane = tid & 63;
    const int code = T * 32 + (lane & 31);
    const int d0 = q * 16 + (lane >> 5) * 8;
    const float* ep = emb + (size_t)code * DD + d0;
    f16x8 oh, ol;
#pragma unroll
    for (int j = 0; j < 8; ++j) {
      float v = ep[j];
      _Float16 hv = (_Float16)v;
      oh[j] = hv;
      ol[j] = (_Float16)(v - (float)hv);
    }
    f16x8* dst = (f16x8*)(ws + WS_BFRAG_F);
    dst[(T * 8 + q) * 64 + lane] = oh;       // p=0: hi plane
    dst[(T * 8 + 4 + q) * 64 + lane] = ol;   // p=1: lo plane
  } else {
    const int k = (b - 32) * 256 + tid;  // 0..1023
    ws[WS_E2 + k] = row_sumsq_np8(emb + (size_t)k * DD);
    if (b == 32 && tid == 0) out[LOSS_OFF] = 0.0f;
  }
}

__launch_bounds__(256, 1)
__global__ void vq_main(const float* __restrict__ x_in,
                        const float* __restrict__ emb,
                        const float* __restrict__ ws_ro,
                        float* __restrict__ out) {
  const int tid = threadIdx.x;
  const int wave = tid >> 6, lane = tid & 63;
  const int c31 = lane & 31, h = lane >> 5;
  const int tokBase = blockIdx.x * 128 + wave * 32;  // 32 tokens per wave

  __shared__ float wsum[4];

  // x2: each lane computes sumsq of token (c31); per-slot x2 via shuffles.
  // row(r) = (r&3) + 8*(r>>2) + 4*h  (the m74/m101 C-row mapping).
  const float x2own =
      row_sumsq_np8(x_in + (size_t)(tokBase + c31) * DD);
  float x2v[16];
#pragma unroll
  for (int r = 0; r < 16; ++r)
    x2v[r] = __shfl(x2own, (r & 3) + 8 * (r >> 2) + 4 * h);

  // A fragments: row = token (c31), k-chunk = h: frag q holds dims
  // q*16 + h*8 .. +8 of this lane's token, split into fp16 hi/lo planes.
  f16x8 ah[4], al[4];
  {
    const float* xr = x_in + (size_t)(tokBase + c31) * DD + h * 8;
#pragma unroll
    for (int q = 0; q < 4; ++q) {
      const float4 v0 = *(const float4*)(xr + q * 16);
      const float4 v1 = *(const float4*)(xr + q * 16 + 4);
      float vv[8] = {v0.x, v0.y, v0.z, v0.w, v1.x, v1.y, v1.z, v1.w};
#pragma unroll
      for (int j = 0; j < 8; ++j) {
        _Float16 hv = (_Float16)vv[j];
        ah[q][j] = hv;
        al[q][j] = (_Float16)(vv[j] - (float)hv);
      }
    }
  }

  float best[16];
  int bidx[16];
#pragma unroll
  for (int r = 0; r < 16; ++r) { best[r] = 3.402823466e38f; bidx[r] = 0; }

  const f16x8* bws2 = (const f16x8*)(ws_ro + WS_BFRAG_F);
  const float* e2p = ws_ro + WS_E2 + c31;

  // Prologue: tile 0 B-frags (hi+lo halves) and e2.
  f16x8 BH[4], BL[4];
#pragma unroll
  for (int q = 0; q < 4; ++q) BH[q] = bws2[(0 * 8 + q) * 64 + lane];
#pragma unroll
  for (int q = 0; q < 4; ++q) BL[q] = bws2[(0 * 8 + 4 + q) * 64 + lane];
  float e2v = e2p[0];

  // Main loop: 32 code-tiles. Per tile: 12 MFMA into one f32x16 acc in the
  // order hihi(q0..3), lohi(q0..3), hilo(q0..3); BH dead after lohi ->
  // prefetch next hi into it; BL dead after hilo -> prefetch next lo.
#pragma unroll 2
  for (int T = 0; T < 31; ++T) {
    f32x16 acc = (f32x16){0.f, 0.f, 0.f, 0.f, 0.f, 0.f, 0.f, 0.f,
                          0.f, 0.f, 0.f, 0.f, 0.f, 0.f, 0.f, 0.f};
#pragma unroll
    for (int q = 0; q < 4; ++q) acc = MFMA32(ah[q], BH[q], acc, 0, 0, 0);
#pragma unroll
    for (int q = 0; q < 4; ++q) acc = MFMA32(al[q], BH[q], acc, 0, 0, 0);
    // BH dead: prefetch tile T+1 hi half + e2.
#pragma unroll
    for (int q = 0; q < 4; ++q) BH[q] = bws2[((T + 1) * 8 + q) * 64 + lane];
    const float e2n = e2p[(T + 1) * 32];
#pragma unroll
    for (int q = 0; q < 4; ++q) acc = MFMA32(ah[q], BL[q], acc, 0, 0, 0);
    // BL dead: prefetch tile T+1 lo half.
#pragma unroll
    for (int q = 0; q < 4; ++q)
      BL[q] = bws2[((T + 1) * 8 + 4 + q) * 64 + lane];
    // First-min update: this lane's code is ncur for ALL 16 token slots.
    const int ncur = T * 32 + c31;
#pragma unroll
    for (int r = 0; r < 16; ++r) {
      float s = __builtin_fmaf(-2.0f, acc[r], x2v[r] + e2v);
      if (s < best[r]) { best[r] = s; bidx[r] = ncur; }
    }
    e2v = e2n;
  }
  {  // tail tile 31 (no prefetch)
    f32x16 acc = (f32x16){0.f, 0.f, 0.f, 0.f, 0.f, 0.f, 0.f, 0.f,
                          0.f, 0.f, 0.f, 0.f, 0.f, 0.f, 0.f, 0.f};
#pragma unroll
    for (int q = 0; q < 4; ++q) acc = MFMA32(ah[q], BH[q], acc, 0, 0, 0);
#pragma unroll
    for (int q = 0; q < 4; ++q) acc = MFMA32(al[q], BH[q], acc, 0, 0, 0);
#pragma unroll
    for (int q = 0; q < 4; ++q) acc = MFMA32(ah[q], BL[q], acc, 0, 0, 0);
    const int ncur = 31 * 32 + c31;
#pragma unroll
    for (int r = 0; r < 16; ++r) {
      float s = __builtin_fmaf(-2.0f, acc[r], x2v[r] + e2v);
      if (s < best[r]) { best[r] = s; bidx[r] = ncur; }
    }
  }

  // Butterfly min across the 32 lanes of each h-group (XOR 1..16 never
  // flips bit 5) -> all 32 lanes hold each slot's winner; equal distances
  // resolve to the smaller idx via the u64 key, matching argmin-first.
  unsigned long long key[16];
#pragma unroll
  for (int r = 0; r < 16; ++r) {
    unsigned long long k =
        ((unsigned long long)sortable_bits(best[r]) << 32) |
        (unsigned int)bidx[r];
#pragma unroll
    for (int m = 1; m < 32; m <<= 1) {
      unsigned long long o = __shfl_xor(k, m);
      k = o < k ? o : k;
    }
    key[r] = k;
  }

  // Fused epilogue: idx store (group lane 0), quant gather+store (16 lanes
  // per group), loss partial decoded from keys (once per token).
  float qsum = 0.0f;
#pragma unroll
  for (int r = 0; r < 16; ++r) {
    const int token = tokBase + (r & 3) + 8 * (r >> 2) + 4 * h;
    const int widx = (int)(unsigned int)key[r];
    if (c31 == 0) {
      out[IDX_OFF + (size_t)token] = (float)widx;
      qsum += unsortable_bits((unsigned int)(key[r] >> 32));
    }
    if (c31 < 16) {
      // 16 lanes x float4 = the winning 256B row, bitwise copy
      const float4 v = ((const float4*)(emb + (size_t)widx * DD))[c31];
      ((float4*)(out + (size_t)token * DD))[c31] = v;
    }
  }

  // qsum held by lanes 0 (h=0 slots) and 32 (h=1 slots); combine, then one
  // atomicAdd per block of the scaled partial (loss cell zeroed by setup).
  float tot = __shfl(qsum, 0) + __shfl(qsum, 32);
  if (lane == 0) wsum[wave] = tot;
  __syncthreads();
  if (tid == 0) {
    // 1.25f / 2^23 is exactly representable; one rounding per block.
    const float scale = 1.25f / (float)QUANT_ELEMS;
    atomicAdd(&out[LOSS_OFF], ((wsum[0] + wsum[1]) + (wsum[2] + wsum[3])) * scale);
  }
}

extern "C" void kernel_launch(void* const* d_in, const int* in_sizes, int n_in,
                              void* d_out, int out_size, void* d_ws, size_t ws_size,
                              hipStream_t stream) {
  const float* x = (const float*)d_in[0];
  const float* emb = (const float*)d_in[1];
  float* out = (float*)d_out;
  float* ws = (float*)d_ws;

  vq_setup<<<36, 256, 0, stream>>>(emb, ws, out);
  vq_main<<<MAIN_BLOCKS, 256, 0, stream>>>(x, emb, ws, out);
}

// Round 11
// 137.886 us; speedup vs baseline: 1.1322x; 1.1322x over previous
//
#include <hip/hip_runtime.h>

// VectorQuantizer: N=131072 tokens, D=64, K=1024 codes.
// out (f32 concat): [0,8388608) quant, [8388608] loss, [8388609,...) idx.
//
// R21: per-block tile-order rotation (L2 hot-line de-convoy) + in-loop
// u64 key-min.
// R20 post-mortem: 32x32 shape regressed (91us, single 12-deep acc chain,
// MfmaUtil 24.5); layouts verified correct (absmax unchanged). Reverted.
// New theory: ALL 1024 blocks walk tiles 0->63 in lockstep, so ~512 waves
// per XCD read the SAME 128 L2 lines (16KB tile) at the same instant. L2
// doesn't broadcast -> same-line requests serialize -> chip-wide hot-line
// convoy. Explains every null: occupancy/prefetch-depth/setprio/SGB/acc-
// pipeline all preserved the global tile phase and inherited the same L2
// service rate (~60% stall, invariant).
// Fix: block b starts its tile walk at (b & 63) -> frag reads spread over
// all 64 tiles (2048 lines) per XCD. Legal because first-min-ascending ==
// min over u64 key (sortable_dist<<32 | idx), which is ORDER-INVARIANT;
// the key-min moves into the update loop (the epilogue butterfly already
// used this exact key, its pack step now disappears). Per-(token,code)
// distance values are bit-identical to R14 (same MFMA products, same
// per-acc order, same fma expression) and min-key == min-dist with
// min-idx tiebreak == reference argmin first-occurrence -> outputs
// bit-identical to R14.
// Base verbatim R14 (best total, VGPR 56): 32 tok/wave, grid 1024x256,
// launch_bounds(256,2), 1-deep bA/bB prefetch, atomicAdd loss fusion,
// 2 launches. Distance math bit-identical to R4-R19: fp16 split-product
// MFMA (hi*hi+lo*hi+hi*lo), np8 x2/e2, s=fma(-2,acc,x2v+e2v), min-key
// tie semantics, butterfly epilogue, bitwise quant copy.

#define KC 1024
#define DD 64
#define NTOK (32 * 4096)
#define QUANT_ELEMS ((size_t)NTOK * DD)        // 8388608
#define LOSS_OFF QUANT_ELEMS
#define IDX_OFF (QUANT_ELEMS + 1)

// ws float-word offsets (layout identical to R10/R12)
#define WS_E2 0                      // 1024 f32
#define WS_BFRAG_F 2048              // 16384 f16x8 = 65536 f32 words

#define MAIN_BLOCKS (NTOK / 128)     // 1024 blocks, 128 tokens each

typedef _Float16 f16x8 __attribute__((ext_vector_type(8)));
typedef float f32x4 __attribute__((ext_vector_type(4)));

__device__ __forceinline__ unsigned int sortable_bits(float f) {
  unsigned int b = __float_as_uint(f);
  return b ^ (unsigned int)(((int)b >> 31) | 0x80000000);
}

__device__ __forceinline__ float unsortable_bits(unsigned int u) {
  unsigned int fb = (u & 0x80000000u) ? (u ^ 0x80000000u) : ~u;
  return __uint_as_float(fb);
}

// np pairwise-8 sum of squares of a 64-float row (bit-identical to R10)
__device__ __forceinline__ float row_sumsq_np8(const float* p) {
  float r[8];
#pragma unroll
  for (int j = 0; j < 8; ++j) r[j] = p[j] * p[j];
#pragma unroll
  for (int i = 1; i < 8; ++i)
#pragma unroll
    for (int j = 0; j < 8; ++j) {
      float v = p[i * 8 + j];
      r[j] += v * v;
    }
  return ((r[0] + r[1]) + (r[2] + r[3])) + ((r[4] + r[5]) + (r[6] + r[7]));
}

// blocks [0,64): B-frag build; [64,68): e2 table (verbatim R10/R12)
// + block 64 tid 0 zeroes the loss accumulator for this iteration.
__global__ void vq_setup(const float* __restrict__ emb,
                         float* __restrict__ ws,
                         float* __restrict__ out) {
  const int b = blockIdx.x;
  const int tid = threadIdx.x;
  if (b < 64) {
    const int nt = b;                  // global tile 0..63 (16 codes each)
    const int f = tid >> 6;            // 0..3: plane(hi/lo) x kstep
    const int lane = tid & 63;
    const int plane = f >> 1, ks = f & 1;
    const int n = nt * 16 + (lane & 15);
    const int kb = ks * 32 + ((lane >> 4) & 3) * 8;
    const float* ep = emb + (size_t)n * DD + kb;
    f16x8 o;
#pragma unroll
    for (int j = 0; j < 8; ++j) {
      float v = ep[j];
      _Float16 h = (_Float16)v;
      o[j] = (plane == 0) ? h : (_Float16)(v - (float)h);
    }
    ((f16x8*)(ws + WS_BFRAG_F))[(nt * 4 + f) * 64 + lane] = o;
  } else {
    const int k = (b - 64) * 256 + tid;  // 0..1023
    ws[WS_E2 + k] = row_sumsq_np8(emb + (size_t)k * DD);
    if (b == 64 && tid == 0) out[LOSS_OFF] = 0.0f;
  }
}

__launch_bounds__(256, 2)
__global__ void vq_main(const float* __restrict__ x_in,
                        const float* __restrict__ emb,
                        const float* __restrict__ ws_ro,
                        float* __restrict__ out) {
  const int tid = threadIdx.x;
  const int wave = tid >> 6, lane = tid & 63;
  const int quad = lane >> 4, l16 = lane & 15;
  const int blockTok = blockIdx.x * 128;
  const int tokBase = blockTok + wave * 32;  // 32 tokens per wave

  __shared__ float E2s[KC];    // 4 KB
  __shared__ float x2s[128];   // per-block token x2
  __shared__ float wsum[4];

  // Stage e2 table to LDS; x2: one row per thread for tid<128
  // (bit-identical np8 -- value depends only on row data, not producer).
#pragma unroll
  for (int i = 0; i < 4; ++i)
    E2s[i * 256 + tid] = ws_ro[WS_E2 + i * 256 + tid];
  if (tid < 128)
    x2s[tid] = row_sumsq_np8(x_in + (size_t)(blockTok + tid) * DD);

  // A fragments: 2 m-sets of 16 tokens; x split into fp16 hi/lo planes.
  f16x8 ah[2][2], al[2][2];
#pragma unroll
  for (int ms = 0; ms < 2; ++ms) {
    const float* xr = x_in + (size_t)(tokBase + ms * 16 + l16) * DD;
#pragma unroll
    for (int ks = 0; ks < 2; ++ks) {
      const float4* p4 = (const float4*)(xr + ks * 32 + quad * 8);
      float4 v0 = p4[0], v1 = p4[1];
      float vv[8] = {v0.x, v0.y, v0.z, v0.w, v1.x, v1.y, v1.z, v1.w};
#pragma unroll
      for (int j = 0; j < 8; ++j) {
        _Float16 h = (_Float16)vv[j];
        ah[ms][ks][j] = h;
        al[ms][ks][j] = (_Float16)(vv[j] - (float)h);
      }
    }
  }

  // Per-slot winner as u64 key (sortable_dist<<32 | idx): min over all
  // codes == min dist with min-idx tiebreak == reference argmin, for ANY
  // tile visitation order.
  unsigned long long key[2][4];
  {
    const unsigned long long kinit =
        ((unsigned long long)sortable_bits(3.402823466e38f) << 32);
#pragma unroll
    for (int ms = 0; ms < 2; ++ms)
#pragma unroll
      for (int r = 0; r < 4; ++r) key[ms][r] = kinit;
  }

  __syncthreads();  // E2s + x2s ready -- the ONLY barrier before epilogue

  // x2 for this lane's C rows: token = tokBase + ms*16 + quad*4 + r
  float x2v[2][4];
#pragma unroll
  for (int ms = 0; ms < 2; ++ms)
#pragma unroll
    for (int r = 0; r < 4; ++r)
      x2v[ms][r] = x2s[wave * 32 + ms * 16 + quad * 4 + r];

  const f16x8* bws = (const f16x8*)(ws_ro + WS_BFRAG_F);

  // Per-tile compute: 12 MFMA (6-product chain per ms, order identical to
  // R4-R19, step-major across the 2 independent chains) + key-min update.
  auto TILE = [&](int nt, const f16x8 (&bf)[4]) {
    const int ncur = nt * 16 + l16;       // this lane's code column
    const float e2v = E2s[ncur];
    f32x4 acc[2];
#pragma unroll
    for (int ms = 0; ms < 2; ++ms) acc[ms] = (f32x4){0.f, 0.f, 0.f, 0.f};
#pragma unroll
    for (int ms = 0; ms < 2; ++ms)
      acc[ms] = __builtin_amdgcn_mfma_f32_16x16x32_f16(ah[ms][0], bf[0], acc[ms], 0, 0, 0);
#pragma unroll
    for (int ms = 0; ms < 2; ++ms)
      acc[ms] = __builtin_amdgcn_mfma_f32_16x16x32_f16(ah[ms][1], bf[1], acc[ms], 0, 0, 0);
#pragma unroll
    for (int ms = 0; ms < 2; ++ms)
      acc[ms] = __builtin_amdgcn_mfma_f32_16x16x32_f16(al[ms][0], bf[0], acc[ms], 0, 0, 0);
#pragma unroll
    for (int ms = 0; ms < 2; ++ms)
      acc[ms] = __builtin_amdgcn_mfma_f32_16x16x32_f16(al[ms][1], bf[1], acc[ms], 0, 0, 0);
#pragma unroll
    for (int ms = 0; ms < 2; ++ms)
      acc[ms] = __builtin_amdgcn_mfma_f32_16x16x32_f16(ah[ms][0], bf[2], acc[ms], 0, 0, 0);
#pragma unroll
    for (int ms = 0; ms < 2; ++ms)
      acc[ms] = __builtin_amdgcn_mfma_f32_16x16x32_f16(ah[ms][1], bf[3], acc[ms], 0, 0, 0);
#pragma unroll
    for (int ms = 0; ms < 2; ++ms)
#pragma unroll
      for (int r = 0; r < 4; ++r) {
        float s = __builtin_fmaf(-2.0f, acc[ms][r], x2v[ms][r] + e2v);
        unsigned long long k =
            ((unsigned long long)sortable_bits(s) << 32) | (unsigned int)ncur;
        if (k < key[ms][r]) key[ms][r] = k;
      }
  };

  // Barrier-free rotated main loop: 64 code-tiles starting at (block&63),
  // 1-deep bA/bB prefetch. Distances are per-tile independent; key-min
  // makes the result order-invariant.
  const int start = blockIdx.x & 63;
  f16x8 bA[4], bB[4];
#pragma unroll
  for (int i = 0; i < 4; ++i) bA[i] = bws[(start * 4 + i) * 64 + lane];

  for (int t = 0; t < 64; t += 2) {
    const int ntB = (start + t + 1) & 63;
#pragma unroll
    for (int i = 0; i < 4; ++i) bB[i] = bws[(ntB * 4 + i) * 64 + lane];
    TILE((start + t) & 63, bA);
    if (t + 2 < 64) {
      const int ntA = (start + t + 2) & 63;
#pragma unroll
      for (int i = 0; i < 4; ++i) bA[i] = bws[(ntA * 4 + i) * 64 + lane];
    }
    TILE(ntB, bB);
  }

  // Butterfly min across each quad's 16 lanes -> ALL lanes hold the winner.
#pragma unroll
  for (int ms = 0; ms < 2; ++ms)
#pragma unroll
    for (int r = 0; r < 4; ++r) {
      unsigned long long k = key[ms][r];
#pragma unroll
      for (int m = 1; m < 16; m <<= 1) {
        unsigned long long o = __shfl_xor(k, m);
        k = o < k ? o : k;
      }
      key[ms][r] = k;
    }

  // Fused epilogue: idx store (quad lane 0), quant gather+store (all lanes),
  // loss partial decoded from keys.
  float qsum = 0.0f;
#pragma unroll
  for (int ms = 0; ms < 2; ++ms)
#pragma unroll
    for (int r = 0; r < 4; ++r) {
      const int token = tokBase + ms * 16 + quad * 4 + r;
      const int widx = (int)(unsigned int)key[ms][r];
      if (l16 == 0) out[IDX_OFF + (size_t)token] = (float)widx;
      // 16 lanes x float4 = the winning 256B row, bitwise copy
      const float4 v = ((const float4*)(emb + (size_t)widx * DD))[l16];
      ((float4*)(out + (size_t)token * DD))[l16] = v;
      qsum += unsortable_bits((unsigned int)(key[ms][r] >> 32));
    }

  // qsum identical across a quad's 16 lanes; sum the 4 quads, then 4 waves,
  // then atomicAdd the scaled partial into the loss cell (zeroed by setup).
  float tot = __shfl(qsum, 0) + __shfl(qsum, 16) +
              __shfl(qsum, 32) + __shfl(qsum, 48);
  if (lane == 0) wsum[wave] = tot;
  __syncthreads();
  if (tid == 0) {
    // 1.25f / 2^23 is exactly representable; one rounding per block.
    const float scale = 1.25f / (float)QUANT_ELEMS;
    atomicAdd(&out[LOSS_OFF], ((wsum[0] + wsum[1]) + (wsum[2] + wsum[3])) * scale);
  }
}

extern "C" void kernel_launch(void* const* d_in, const int* in_sizes, int n_in,
                              void* d_out, int out_size, void* d_ws, size_t ws_size,
                              hipStream_t stream) {
  const float* x = (const float*)d_in[0];
  const float* emb = (const float*)d_in[1];
  float* out = (float*)d_out;
  float* ws = (float*)d_ws;

  vq_setup<<<68, 256, 0, stream>>>(emb, ws, out);
  vq_main<<<MAIN_BLOCKS, 256, 0, stream>>>(x, emb, ws, out);
}